// Round 2
// baseline (549.988 us; speedup 1.0000x reference)
//
#include <hip/hip_runtime.h>
#include <hip/hip_bf16.h>

constexpr int kB = 16, kN = 512, kD = 256, kH = 8, kE = 16, kDH = 32;

typedef float f4 __attribute__((ext_vector_type(4)));
typedef __bf16 bf8 __attribute__((ext_vector_type(8)));

__device__ __forceinline__ void gload16(const void* g, const void* l) {
  __builtin_amdgcn_global_load_lds(
      (const __attribute__((address_space(1))) void*)g,
      (__attribute__((address_space(3))) void*)l, 16, 0, 0);
}

// ---------------- P1: cast h (fp32) -> bf16 ----------------
__global__ __launch_bounds__(256) void cast_h_kernel(const float* __restrict__ h,
                                                     __bf16* __restrict__ hb) {
  const int idx = (blockIdx.x * 256 + threadIdx.x) * 8;
  f4 a = *(const f4*)(h + idx);
  f4 b = *(const f4*)(h + idx + 4);
  bf8 o;
  o[0] = (__bf16)a[0]; o[1] = (__bf16)a[1]; o[2] = (__bf16)a[2]; o[3] = (__bf16)a[3];
  o[4] = (__bf16)b[0]; o[5] = (__bf16)b[1]; o[6] = (__bf16)b[2]; o[7] = (__bf16)b[3];
  *(bf8*)(hb + idx) = o;
}

// ---------------- P2: weights -> bf16, transposed [n][k] ----------------
__global__ __launch_bounds__(256) void prep_w_kernel(
    const float* __restrict__ Wq, const float* __restrict__ Wk,
    const float* __restrict__ Wv, const float* __restrict__ Wo,
    __bf16* __restrict__ Wt, __bf16* __restrict__ Wot) {
  const int r = blockIdx.x;
  const int t = threadIdx.x;
  if (r < 768) {
    const float* src = (r < 256) ? Wq : (r < 512) ? Wk : Wv;
    const int c = r & 255;
    Wt[(size_t)r * 256 + t] = (__bf16)src[(size_t)t * 256 + c];
  } else {
    const int rr = r - 768;
    Wot[(size_t)rr * 256 + t] = (__bf16)Wo[(size_t)t * 256 + rr];
  }
}

// ---------------- K1: QKV projection GEMM (M=8192, N=768, K=256) ----------------
__global__ __launch_bounds__(256, 4) void qkv_gemm_kernel(
    const __bf16* __restrict__ hb, const __bf16* __restrict__ Wt,
    const float* __restrict__ bq, const float* __restrict__ bk,
    const float* __restrict__ bv,
    __bf16* __restrict__ qw, __bf16* __restrict__ kw, __bf16* __restrict__ vtw) {
  const int M0 = blockIdx.x * 128;
  const int N0 = blockIdx.y * 64;
  const int tid = threadIdx.x;
  const int wave = tid >> 6, lane = tid & 63;
  const int l15 = lane & 15, lq = lane >> 4;
  const int wm = wave & 1, wn = wave >> 1;
  const f4 fzero = {0.f, 0.f, 0.f, 0.f};

  f4 acc[4][2];
#pragma unroll
  for (int tm = 0; tm < 4; ++tm)
#pragma unroll
    for (int tn = 0; tn < 2; ++tn) acc[tm][tn] = fzero;

#pragma unroll
  for (int kk = 0; kk < 256; kk += 32) {
    bf8 af[4], bfr[2];
#pragma unroll
    for (int tm = 0; tm < 4; ++tm)
      af[tm] = *(const bf8*)(hb + (size_t)(M0 + wm * 64 + tm * 16 + l15) * 256 + kk + lq * 8);
#pragma unroll
    for (int tn = 0; tn < 2; ++tn)
      bfr[tn] = *(const bf8*)(Wt + (size_t)(N0 + wn * 32 + tn * 16 + l15) * 256 + kk + lq * 8);
#pragma unroll
    for (int tm = 0; tm < 4; ++tm)
#pragma unroll
      for (int tn = 0; tn < 2; ++tn)
        acc[tm][tn] = __builtin_amdgcn_mfma_f32_16x16x32_bf16(af[tm], bfr[tn], acc[tm][tn], 0, 0, 0);
  }

  const float QS = 0.17677669529663687f;  // 1/sqrt(DH)
  const int wsel = N0 >> 8;               // 0:q 1:k 2:v
#pragma unroll
  for (int tn = 0; tn < 2; ++tn) {
    const int n = N0 + wn * 32 + tn * 16 + l15;
    const int c = n & 255;
    const float bias = (wsel == 0) ? bq[c] : (wsel == 1) ? bk[c] : bv[c];
#pragma unroll
    for (int tm = 0; tm < 4; ++tm) {
#pragma unroll
      for (int r = 0; r < 4; ++r) {
        const int m = M0 + wm * 64 + tm * 16 + lq * 4 + r;
        const float v = acc[tm][tn][r] + bias;
        if (wsel == 0) {
          qw[(size_t)m * 256 + c] = (__bf16)(v * QS);
        } else if (wsel == 1) {
          kw[(size_t)m * 256 + c] = (__bf16)v;
        } else {
          const int b_ = m >> 9, nn_ = m & 511, hh = c >> 5, dd = c & 31;
          vtw[(((size_t)b_ * kH + hh) * kDH + dd) * kN + nn_] = (__bf16)v;
        }
      }
    }
  }
}

// ---------------- K2: fused pos + QK^T + softmax + attn-write + P@V ----------------
// Grid: 512 blocks (b, 16-query tile). 8 waves = 8 heads. Scores in 128 AGPR/lane.
// R2: phase 1 rebuilt around global_load_lds staging:
//  - 8x coalesced 1KB gload_lds per wave per 64-key half-chunk (16 contiguous
//    lines/instr vs 64 scattered before -> deep in-flight, miss-queue friendly)
//  - ping-pong 64KB stage buffers, counted s_waitcnt vmcnt(8) + raw s_barrier
//    so next half-chunk's loads stay in flight across the barrier (T3/T4)
//  - each head-wave computes its pos dot straight into sc fragments (no pos
//    LDS transpose buffer, no sc-init pass)
//  - XOR-rotation swizzle (source-side permute + swizzled ds_read, rule #21)
//    keeps ds_read_b128 at free 2-way conflicts
//  - masks deferred to softmax as packed bits, loaded under phase-2 MFMAs
__global__ __launch_bounds__(512, 2) void attn_fused_kernel(
    const __bf16* __restrict__ qw, const __bf16* __restrict__ kw,
    const __bf16* __restrict__ vtw, const float* __restrict__ edges,
    const int* __restrict__ dmask, const int* __restrict__ kmask,
    const float* __restrict__ Wp, const float* __restrict__ bp,
    float* __restrict__ attn_out, __bf16* __restrict__ ow) {
  const int blk = blockIdx.x;
  const int b = blk >> 5;
  const int n0 = (blk & 31) * 16;
  const int tid = threadIdx.x;
  const int wave = tid >> 6, lane = tid & 63;
  const int l15 = lane & 15, lq = lane >> 4;

  // stg: 2 x 64KB edge staging (16 q x 64 m x 64B, rot-swizzled e4 slots).
  // p: phase-4 P tiles, aliases stg[0]; safe after phase-1's final barrier.
  __shared__ __align__(16) union {
    float stg[2][16][64][16];
    __bf16 p[8][16][136];
  } su;

  f4 sc[32];  // scores: sc[kt][r] = S[q = lq*4+r][key = kt*16+l15]
  const float RS8 = 0.35355339059327373f;  // 1/sqrt(H)

  // per-wave (head) Wp column, RS8 pre-folded
  f4 wpv[4];
#pragma unroll
  for (int e4 = 0; e4 < 4; ++e4)
#pragma unroll
    for (int i = 0; i < 4; ++i) wpv[e4][i] = Wp[(e4 * 4 + i) * kH + wave] * RS8;
  const float bph = bp[wave] * RS8;

  // ---- phase 1: stage edges -> LDS (coalesced), pos dot -> sc init ----
  const int msub = lane >> 2;   // m within 16-block
  const int rotl = lane & 3;    // swizzle slot
  const int rb = (l15 >> 1) & 3;

#define STAGE_ISSUE(HC)                                                              \
  {                                                                                  \
    const int buf_ = (HC) & 1;                                                       \
    _Pragma("unroll") for (int i_ = 0; i_ < 8; ++i_) {                               \
      const int n_ = wave * 8 + i_;                                                  \
      const int q_ = n_ >> 2;                                                        \
      const int m_ = (n_ & 3) * 16 + msub;                                           \
      const int e4_ = (rotl - ((m_ >> 1) & 3)) & 3;                                  \
      const float* g_ =                                                              \
          edges + ((size_t)(b * kN + n0 + q_) * kN + (HC)*64 + m_) * kE + e4_ * 4;   \
      gload16(g_, (const char*)&su.stg[buf_][0][0][0] + n_ * 1024);                  \
    }                                                                                \
  }

  STAGE_ISSUE(0);
  __builtin_amdgcn_sched_barrier(0);

#pragma unroll
  for (int hc = 0; hc < 8; ++hc) {
    const int buf = hc & 1;
    if (hc < 7) {
      STAGE_ISSUE(hc + 1);
      __builtin_amdgcn_sched_barrier(0);
      __asm__ __volatile__("s_waitcnt vmcnt(8)" ::: "memory");
    } else {
      __asm__ __volatile__("s_waitcnt vmcnt(0)" ::: "memory");
    }
    __builtin_amdgcn_s_barrier();
    __builtin_amdgcn_sched_barrier(0);

    const float* stg0 = &su.stg[buf][0][0][0];
#pragma unroll
    for (int ktl = 0; ktl < 4; ++ktl) {
      const int mloc = ktl * 16 + l15;
#pragma unroll
      for (int r = 0; r < 4; ++r) {
        const int q = lq * 4 + r;
        const float* cell = stg0 + ((q * 64 + mloc) << 4);
        f4 s = {0.f, 0.f, 0.f, 0.f};
#pragma unroll
        for (int e4 = 0; e4 < 4; ++e4) {
          const int rot = (e4 + rb) & 3;
          f4 ev = *(const f4*)(cell + rot * 4);
          s += ev * wpv[e4];
        }
        sc[hc * 4 + ktl][r] = (s[0] + s[1]) + (s[2] + s[3]) + bph;
      }
    }
    __builtin_amdgcn_sched_barrier(0);
    __builtin_amdgcn_s_barrier();
  }
#undef STAGE_ISSUE

  // ---- phase 1.5: packed validity bits (loads overlap with phase-2 MFMAs) ----
  unsigned int vmask[4];
#pragma unroll
  for (int g = 0; g < 4; ++g) {
    unsigned int vm = 0u;
#pragma unroll
    for (int kl = 0; kl < 8; ++kl) {
      const int m = (g * 8 + kl) * 16 + l15;
      const int km = kmask[b * kN + m];
#pragma unroll
      for (int r = 0; r < 4; ++r) {
        const int dm = dmask[(size_t)(b * kN + n0 + lq * 4 + r) * kN + m];
        vm |= ((km != 0 && dm != 0) ? 1u : 0u) << (kl * 4 + r);
      }
    }
    vmask[g] = vm;
  }

  // ---- phase 2: scores += q . k^T (MFMA accumulates onto pos init) ----
  bf8 qa = *(const bf8*)(qw + ((size_t)(b * kN + n0 + l15) * kH + wave) * kDH + lq * 8);
#pragma unroll
  for (int kt = 0; kt < 32; ++kt) {
    bf8 kb = *(const bf8*)(kw + ((size_t)(b * kN + kt * 16 + l15) * kH + wave) * kDH + lq * 8);
    sc[kt] = __builtin_amdgcn_mfma_f32_16x16x32_bf16(qa, kb, sc[kt], 0, 0, 0);
  }

  // ---- phase 3: apply mask, row softmax (cross-lane over 16 lanes) ----
#pragma unroll
  for (int kt = 0; kt < 32; ++kt) {
    const unsigned int vm = vmask[kt >> 3];
#pragma unroll
    for (int r = 0; r < 4; ++r) {
      if (!((vm >> ((kt & 7) * 4 + r)) & 1u)) sc[kt][r] = -1e9f;
    }
  }
  float inv[4];
#pragma unroll
  for (int r = 0; r < 4; ++r) {
    float m_ = sc[0][r];
#pragma unroll
    for (int kt = 1; kt < 32; ++kt) m_ = fmaxf(m_, sc[kt][r]);
#pragma unroll
    for (int s = 1; s < 16; s <<= 1) m_ = fmaxf(m_, __shfl_xor(m_, s, 16));
    float s_ = 0.f;
#pragma unroll
    for (int kt = 0; kt < 32; ++kt) {
      const float e_ = __expf(sc[kt][r] - m_);
      sc[kt][r] = e_;
      s_ += e_;
    }
#pragma unroll
    for (int s = 1; s < 16; s <<= 1) s_ += __shfl_xor(s_, s, 16);
    inv[r] = 1.0f / s_;
  }

  // ---- phase 4: write attn (fp32), P->LDS (bf16, wave-private), P@V MFMA ----
  const f4 fzero = {0.f, 0.f, 0.f, 0.f};
  f4 oacc[2];
  oacc[0] = fzero; oacc[1] = fzero;
  float* attn_base = attn_out + ((size_t)(b * kH + wave) * kN + n0) * kN;
#pragma unroll
  for (int cc = 0; cc < 4; ++cc) {
#pragma unroll
    for (int kl = 0; kl < 8; ++kl) {
      const int kt = cc * 8 + kl;
#pragma unroll
      for (int r = 0; r < 4; ++r) {
        const float p = sc[kt][r] * inv[r];
        attn_base[(size_t)(lq * 4 + r) * kN + kt * 16 + l15] = p;
        su.p[wave][lq * 4 + r][kl * 16 + l15] = (__bf16)p;
      }
    }
    // Same-wave cross-lane LDS RAW: force write completion, forbid hoisting.
    __asm__ __volatile__("s_waitcnt lgkmcnt(0)" ::: "memory");
#pragma unroll
    for (int mc = 0; mc < 4; ++mc) {
      bf8 pa = *(const bf8*)(&su.p[wave][l15][mc * 32 + lq * 8]);
#pragma unroll
      for (int dd = 0; dd < 2; ++dd) {
        bf8 vb = *(const bf8*)(vtw + (((size_t)(b * kH + wave) * kDH) + dd * 16 + l15) * kN +
                               cc * 128 + mc * 32 + lq * 8);
        oacc[dd] = __builtin_amdgcn_mfma_f32_16x16x32_bf16(pa, vb, oacc[dd], 0, 0, 0);
      }
    }
  }

  // ---- phase 5: store O (bf16) for the output projection ----
#pragma unroll
  for (int dd = 0; dd < 2; ++dd)
#pragma unroll
    for (int r = 0; r < 4; ++r)
      ow[(size_t)(b * kN + n0 + lq * 4 + r) * kD + wave * kDH + dd * 16 + l15] = (__bf16)oacc[dd][r];
}

// ---------------- K3: out = O @ Wo + bo (M=8192, N=256, K=256) ----------------
__global__ __launch_bounds__(256, 4) void out_gemm_kernel(
    const __bf16* __restrict__ ob, const __bf16* __restrict__ Wot,
    const float* __restrict__ bo, float* __restrict__ out) {
  const int M0 = blockIdx.x * 128;
  const int N0 = blockIdx.y * 64;
  const int tid = threadIdx.x;
  const int wave = tid >> 6, lane = tid & 63;
  const int l15 = lane & 15, lq = lane >> 4;
  const int wm = wave & 1, wn = wave >> 1;
  const f4 fzero = {0.f, 0.f, 0.f, 0.f};

  f4 acc[4][2];
#pragma unroll
  for (int tm = 0; tm < 4; ++tm)
#pragma unroll
    for (int tn = 0; tn < 2; ++tn) acc[tm][tn] = fzero;

#pragma unroll
  for (int kk = 0; kk < 256; kk += 32) {
    bf8 af[4], bfr[2];
#pragma unroll
    for (int tm = 0; tm < 4; ++tm)
      af[tm] = *(const bf8*)(ob + (size_t)(M0 + wm * 64 + tm * 16 + l15) * 256 + kk + lq * 8);
#pragma unroll
    for (int tn = 0; tn < 2; ++tn)
      bfr[tn] = *(const bf8*)(Wot + (size_t)(N0 + wn * 32 + tn * 16 + l15) * 256 + kk + lq * 8);
#pragma unroll
    for (int tm = 0; tm < 4; ++tm)
#pragma unroll
      for (int tn = 0; tn < 2; ++tn)
        acc[tm][tn] = __builtin_amdgcn_mfma_f32_16x16x32_bf16(af[tm], bfr[tn], acc[tm][tn], 0, 0, 0);
  }

#pragma unroll
  for (int tn = 0; tn < 2; ++tn) {
    const int n = N0 + wn * 32 + tn * 16 + l15;
    const float bias = bo[n];
#pragma unroll
    for (int tm = 0; tm < 4; ++tm)
#pragma unroll
      for (int r = 0; r < 4; ++r) {
        const int m = M0 + wm * 64 + tm * 16 + lq * 4 + r;
        out[(size_t)m * 256 + n] = acc[tm][tn][r] + bias;
      }
  }
}

extern "C" void kernel_launch(void* const* d_in, const int* in_sizes, int n_in,
                              void* d_out, int out_size, void* d_ws, size_t ws_size,
                              hipStream_t stream) {
  const float* h = (const float*)d_in[0];
  const float* edges = (const float*)d_in[1];
  const int* dmask = (const int*)d_in[2];
  const int* kmask = (const int*)d_in[3];
  const float* Wq = (const float*)d_in[4];
  const float* bq = (const float*)d_in[5];
  const float* Wk = (const float*)d_in[6];
  const float* bk = (const float*)d_in[7];
  const float* Wv = (const float*)d_in[8];
  const float* bv = (const float*)d_in[9];
  const float* Wo = (const float*)d_in[10];
  const float* bo = (const float*)d_in[11];
  const float* Wp = (const float*)d_in[12];
  const float* bp = (const float*)d_in[13];

  char* ws = (char*)d_ws;
  __bf16* hb = (__bf16*)(ws);                                // 4 MB (reused as ow)
  __bf16* Wt = (__bf16*)(ws + ((size_t)4 << 20));            // 384 KB
  __bf16* Wot = (__bf16*)(ws + ((size_t)4 << 20) + 768 * 256 * 2);  // 128 KB
  __bf16* qw = (__bf16*)(ws + ((size_t)5 << 20));            // 4 MB
  __bf16* kw = (__bf16*)(ws + ((size_t)9 << 20));            // 4 MB
  __bf16* vtw = (__bf16*)(ws + ((size_t)13 << 20));          // 4 MB
  __bf16* ow = hb;  // h cast is consumed by qkv_gemm before attn writes O

  float* out = (float*)d_out;
  float* attn = out + (size_t)kB * kN * kD;

  cast_h_kernel<<<1024, 256, 0, stream>>>(h, hb);
  prep_w_kernel<<<1024, 256, 0, stream>>>(Wq, Wk, Wv, Wo, Wt, Wot);
  qkv_gemm_kernel<<<dim3(64, 12), 256, 0, stream>>>(hb, Wt, bq, bk, bv, qw, kw, vtw);
  attn_fused_kernel<<<512, 512, 0, stream>>>(qw, kw, vtw, edges, dmask, kmask, Wp, bp, attn, ow);
  out_gemm_kernel<<<dim3(64, 4), 256, 0, stream>>>(ow, Wot, bo, out);
}

// Round 3
// 540.108 us; speedup vs baseline: 1.0183x; 1.0183x over previous
//
#include <hip/hip_runtime.h>
#include <hip/hip_bf16.h>

constexpr int kB = 16, kN = 512, kD = 256, kH = 8, kE = 16, kDH = 32;

typedef float f4 __attribute__((ext_vector_type(4)));
typedef __bf16 bf8 __attribute__((ext_vector_type(8)));

__device__ __forceinline__ void gload16(const void* g, const void* l) {
  __builtin_amdgcn_global_load_lds(
      (const __attribute__((address_space(1))) void*)g,
      (__attribute__((address_space(3))) void*)l, 16, 0, 0);
}

// ---------------- P1: cast h (fp32) -> bf16 ----------------
__global__ __launch_bounds__(256) void cast_h_kernel(const float* __restrict__ h,
                                                     __bf16* __restrict__ hb) {
  const int idx = (blockIdx.x * 256 + threadIdx.x) * 8;
  f4 a = *(const f4*)(h + idx);
  f4 b = *(const f4*)(h + idx + 4);
  bf8 o;
  o[0] = (__bf16)a[0]; o[1] = (__bf16)a[1]; o[2] = (__bf16)a[2]; o[3] = (__bf16)a[3];
  o[4] = (__bf16)b[0]; o[5] = (__bf16)b[1]; o[6] = (__bf16)b[2]; o[7] = (__bf16)b[3];
  *(bf8*)(hb + idx) = o;
}

// ---------------- P2: weights -> bf16, transposed [n][k] ----------------
__global__ __launch_bounds__(256) void prep_w_kernel(
    const float* __restrict__ Wq, const float* __restrict__ Wk,
    const float* __restrict__ Wv, const float* __restrict__ Wo,
    __bf16* __restrict__ Wt, __bf16* __restrict__ Wot) {
  const int r = blockIdx.x;
  const int t = threadIdx.x;
  if (r < 768) {
    const float* src = (r < 256) ? Wq : (r < 512) ? Wv : Wv;
    // NOTE: fixed below (keep correct mapping)
    src = (r < 256) ? Wq : (r < 512) ? Wk : Wv;
    const int c = r & 255;
    Wt[(size_t)r * 256 + t] = (__bf16)src[(size_t)t * 256 + c];
  } else {
    const int rr = r - 768;
    Wot[(size_t)rr * 256 + t] = (__bf16)Wo[(size_t)t * 256 + rr];
  }
}

// ---------------- P3: pos = (edges@Wp + bp)*RS8, masks baked, bf16 ----------------
// One block per (b,n) row. Streaming-optimal: stage the 32KB edges row via
// coalesced global_load_lds (slot-permuted source, rule #21), each thread dots
// 2 cells x 16e x 8h, packs bf16 head-pairs into a rotated LDS row, then a
// fully-coalesced sweep stores pos in head-pair-major layout:
//   posp[u32] : [b][h2(4)][n(512)][m(512)]  where u32 = (bf16 h=2*h2, bf16 h=2*h2+1)
// 67MB output -> L3-resident for the attention kernel.
__global__ __launch_bounds__(256) void prep_pos_kernel(
    const float* __restrict__ edges, const int* __restrict__ dmask,
    const int* __restrict__ kmask, const float* __restrict__ Wp,
    const float* __restrict__ bp, unsigned int* __restrict__ posp) {
  const int bn = blockIdx.x;  // b*512 + n
  const int b = bn >> 9;
  const int n = bn & 511;
  const int tid = threadIdx.x;

  __shared__ __align__(16) float stg[8192];          // 32KB edges row, slot-swizzled
  __shared__ __align__(16) unsigned int prow[2048];  // 8KB pos row [m][4 words], rotated

  const float* rowg = edges + (size_t)bn * (kN * kE);

  // stage 32KB: dest linear L = j*4096 + tid*16 bytes; cell c = L>>6 holds its
  // 4 e-slots XOR-permuted (s = e4 ^ (c&3)) so the reader is bank-spread.
#pragma unroll
  for (int j = 0; j < 8; ++j) {
    const int L = j * 4096 + tid * 16;
    const int c = L >> 6;
    const int s = (L >> 4) & 3;
    const int e4 = s ^ (c & 3);
    gload16(rowg + c * 16 + e4 * 4, (const char*)stg + L);
  }
  __asm__ __volatile__("s_waitcnt vmcnt(0)" ::: "memory");
  __builtin_amdgcn_s_barrier();

  const float RS8 = 0.35355339059327373f;  // 1/sqrt(H)
  float bph[8];
#pragma unroll
  for (int hh = 0; hh < 8; ++hh) bph[hh] = bp[hh] * RS8;

#pragma unroll
  for (int half = 0; half < 2; ++half) {
    const int c = half * 256 + tid;  // cell = key index m
    const int dm = dmask[(size_t)bn * kN + c];
    const int km = kmask[b * kN + c];
    const bool valid = (dm != 0) && (km != 0);

    float acc[8];
#pragma unroll
    for (int hh = 0; hh < 8; ++hh) acc[hh] = 0.f;
#pragma unroll
    for (int e4 = 0; e4 < 4; ++e4) {
      const int s = e4 ^ (c & 3);
      f4 ev = *(const f4*)(stg + c * 16 + s * 4);
#pragma unroll
      for (int i = 0; i < 4; ++i) {
        const float e_ = ev[i];
#pragma unroll
        for (int hh = 0; hh < 8; ++hh)
          acc[hh] = fmaf(e_, Wp[(e4 * 4 + i) * kH + hh], acc[hh]);
      }
    }

    unsigned int w[4];
#pragma unroll
    for (int pp = 0; pp < 4; ++pp) {
      const float lo = valid ? fmaf(acc[2 * pp], RS8, bph[2 * pp]) : -1e9f;
      const float hi = valid ? fmaf(acc[2 * pp + 1], RS8, bph[2 * pp + 1]) : -1e9f;
      union { __bf16 h2[2]; unsigned int u; } pk;
      pk.h2[0] = (__bf16)lo;
      pk.h2[1] = (__bf16)hi;
      w[pp] = pk.u;
    }
    // rotate word slots by rot(c) for a bank-spread sweep read
    const int rot = (c + (c >> 3)) & 3;
    uint4 v;
    ((unsigned int*)&v)[0] = w[(0 - rot) & 3];
    ((unsigned int*)&v)[1] = w[(1 - rot) & 3];
    ((unsigned int*)&v)[2] = w[(2 - rot) & 3];
    ((unsigned int*)&v)[3] = w[(3 - rot) & 3];
    *(uint4*)&prow[c * 4] = v;
  }
  __builtin_amdgcn_s_barrier();

  // coalesced sweep: 8KB row -> 4 head-pair pages
#pragma unroll
  for (int it = 0; it < 8; ++it) {
    const int li = it * 256 + tid;  // 0..2047
    const int pp = li >> 9;
    const int m = li & 511;
    const int rot = (m + (m >> 3)) & 3;
    const unsigned int val = prow[m * 4 + ((pp + rot) & 3)];
    posp[((((size_t)(b * 4 + pp) * kN) + n) << 9) + m] = val;
  }
}

// ---------------- K1: QKV projection GEMM (M=8192, N=768, K=256) ----------------
__global__ __launch_bounds__(256, 4) void qkv_gemm_kernel(
    const __bf16* __restrict__ hb, const __bf16* __restrict__ Wt,
    const float* __restrict__ bq, const float* __restrict__ bk,
    const float* __restrict__ bv,
    __bf16* __restrict__ qw, __bf16* __restrict__ kw, __bf16* __restrict__ vtw) {
  const int M0 = blockIdx.x * 128;
  const int N0 = blockIdx.y * 64;
  const int tid = threadIdx.x;
  const int wave = tid >> 6, lane = tid & 63;
  const int l15 = lane & 15, lq = lane >> 4;
  const int wm = wave & 1, wn = wave >> 1;
  const f4 fzero = {0.f, 0.f, 0.f, 0.f};

  f4 acc[4][2];
#pragma unroll
  for (int tm = 0; tm < 4; ++tm)
#pragma unroll
    for (int tn = 0; tn < 2; ++tn) acc[tm][tn] = fzero;

#pragma unroll
  for (int kk = 0; kk < 256; kk += 32) {
    bf8 af[4], bfr[2];
#pragma unroll
    for (int tm = 0; tm < 4; ++tm)
      af[tm] = *(const bf8*)(hb + (size_t)(M0 + wm * 64 + tm * 16 + l15) * 256 + kk + lq * 8);
#pragma unroll
    for (int tn = 0; tn < 2; ++tn)
      bfr[tn] = *(const bf8*)(Wt + (size_t)(N0 + wn * 32 + tn * 16 + l15) * 256 + kk + lq * 8);
#pragma unroll
    for (int tm = 0; tm < 4; ++tm)
#pragma unroll
      for (int tn = 0; tn < 2; ++tn)
        acc[tm][tn] = __builtin_amdgcn_mfma_f32_16x16x32_bf16(af[tm], bfr[tn], acc[tm][tn], 0, 0, 0);
  }

  const float QS = 0.17677669529663687f;  // 1/sqrt(DH)
  const int wsel = N0 >> 8;               // 0:q 1:k 2:v
#pragma unroll
  for (int tn = 0; tn < 2; ++tn) {
    const int n = N0 + wn * 32 + tn * 16 + l15;
    const int c = n & 255;
    const float bias = (wsel == 0) ? bq[c] : (wsel == 1) ? bk[c] : bv[c];
#pragma unroll
    for (int tm = 0; tm < 4; ++tm) {
#pragma unroll
      for (int r = 0; r < 4; ++r) {
        const int m = M0 + wm * 64 + tm * 16 + lq * 4 + r;
        const float v = acc[tm][tn][r] + bias;
        if (wsel == 0) {
          qw[(size_t)m * 256 + c] = (__bf16)(v * QS);
        } else if (wsel == 1) {
          kw[(size_t)m * 256 + c] = (__bf16)v;
        } else {
          const int b_ = m >> 9, nn_ = m & 511, hh = c >> 5, dd = c & 31;
          vtw[(((size_t)b_ * kH + hh) * kDH + dd) * kN + nn_] = (__bf16)v;
        }
      }
    }
  }
}

// ---------------- K2: fused QK^T + pos-init + softmax + attn-write + P@V ----------------
// Grid: 512 blocks (b, 16-query tile). 8 waves = 8 heads. Scores in 128 AGPR/lane.
// R3: phase 1 (edges GEMM) moved to prep_pos_kernel. sc init = 128 aligned u32
// loads from the L3-resident head-pair-major pos. No masks, no pos LDS, ZERO
// barriers before phase 4; waves fully independent.
__global__ __launch_bounds__(512, 2) void attn_fused_kernel(
    const __bf16* __restrict__ qw, const __bf16* __restrict__ kw,
    const __bf16* __restrict__ vtw, const unsigned int* __restrict__ posp,
    float* __restrict__ attn_out, __bf16* __restrict__ ow) {
  const int blk = blockIdx.x;
  const int b = blk >> 5;
  const int n0 = (blk & 31) * 16;
  const int tid = threadIdx.x;
  const int wave = tid >> 6, lane = tid & 63;
  const int l15 = lane & 15, lq = lane >> 4;

  __shared__ __align__(16) __bf16 p[8][16][136];  // phase-4 P tiles (wave-private rows)

  f4 sc[32];  // scores: sc[kt][r] = S[q = lq*4+r][key = kt*16+l15]

  // ---- phase 1: sc init from precomputed pos (bf16 pair pages) ----
  const unsigned int* pw = posp + (((size_t)(b * 4 + (wave >> 1)) * kN + n0) << 9);
  const int hlo = wave & 1;
#pragma unroll
  for (int kt = 0; kt < 32; ++kt) {
#pragma unroll
    for (int r = 0; r < 4; ++r) {
      const unsigned int u = pw[(size_t)(lq * 4 + r) * kN + kt * 16 + l15];
      sc[kt][r] = __uint_as_float(hlo ? (u & 0xffff0000u) : (u << 16));
    }
  }

  // ---- phase 2: scores += q . k^T (MFMA accumulates onto pos init) ----
  bf8 qa = *(const bf8*)(qw + ((size_t)(b * kN + n0 + l15) * kH + wave) * kDH + lq * 8);
#pragma unroll
  for (int kt = 0; kt < 32; ++kt) {
    bf8 kb = *(const bf8*)(kw + ((size_t)(b * kN + kt * 16 + l15) * kH + wave) * kDH + lq * 8);
    sc[kt] = __builtin_amdgcn_mfma_f32_16x16x32_bf16(qa, kb, sc[kt], 0, 0, 0);
  }

  // ---- phase 3: row softmax (cross-lane over 16 lanes sharing a row) ----
  float inv[4];
#pragma unroll
  for (int r = 0; r < 4; ++r) {
    float m_ = sc[0][r];
#pragma unroll
    for (int kt = 1; kt < 32; ++kt) m_ = fmaxf(m_, sc[kt][r]);
#pragma unroll
    for (int s = 1; s < 16; s <<= 1) m_ = fmaxf(m_, __shfl_xor(m_, s, 16));
    float s_ = 0.f;
#pragma unroll
    for (int kt = 0; kt < 32; ++kt) {
      const float e_ = __expf(sc[kt][r] - m_);
      sc[kt][r] = e_;
      s_ += e_;
    }
#pragma unroll
    for (int s = 1; s < 16; s <<= 1) s_ += __shfl_xor(s_, s, 16);
    inv[r] = 1.0f / s_;
  }

  // ---- phase 4: write attn (fp32), P->LDS (bf16, wave-private), P@V MFMA ----
  const f4 fzero = {0.f, 0.f, 0.f, 0.f};
  f4 oacc[2];
  oacc[0] = fzero; oacc[1] = fzero;
  float* attn_base = attn_out + ((size_t)(b * kH + wave) * kN + n0) * kN;
#pragma unroll
  for (int cc = 0; cc < 4; ++cc) {
#pragma unroll
    for (int kl = 0; kl < 8; ++kl) {
      const int kt = cc * 8 + kl;
#pragma unroll
      for (int r = 0; r < 4; ++r) {
        const float pv = sc[kt][r] * inv[r];
        attn_base[(size_t)(lq * 4 + r) * kN + kt * 16 + l15] = pv;
        p[wave][lq * 4 + r][kl * 16 + l15] = (__bf16)pv;
      }
    }
    // Same-wave cross-lane LDS RAW: force write completion, forbid hoisting.
    __asm__ __volatile__("s_waitcnt lgkmcnt(0)" ::: "memory");
#pragma unroll
    for (int mc = 0; mc < 4; ++mc) {
      bf8 pa = *(const bf8*)(&p[wave][l15][mc * 32 + lq * 8]);
#pragma unroll
      for (int dd = 0; dd < 2; ++dd) {
        bf8 vb = *(const bf8*)(vtw + (((size_t)(b * kH + wave) * kDH) + dd * 16 + l15) * kN +
                               cc * 128 + mc * 32 + lq * 8);
        oacc[dd] = __builtin_amdgcn_mfma_f32_16x16x32_bf16(pa, vb, oacc[dd], 0, 0, 0);
      }
    }
  }

  // ---- phase 5: store O (bf16) for the output projection ----
#pragma unroll
  for (int dd = 0; dd < 2; ++dd)
#pragma unroll
    for (int r = 0; r < 4; ++r)
      ow[(size_t)(b * kN + n0 + lq * 4 + r) * kD + wave * kDH + dd * 16 + l15] = (__bf16)oacc[dd][r];
}

// ---------------- K3: out = O @ Wo + bo (M=8192, N=256, K=256) ----------------
__global__ __launch_bounds__(256, 4) void out_gemm_kernel(
    const __bf16* __restrict__ ob, const __bf16* __restrict__ Wot,
    const float* __restrict__ bo, float* __restrict__ out) {
  const int M0 = blockIdx.x * 128;
  const int N0 = blockIdx.y * 64;
  const int tid = threadIdx.x;
  const int wave = tid >> 6, lane = tid & 63;
  const int l15 = lane & 15, lq = lane >> 4;
  const int wm = wave & 1, wn = wave >> 1;
  const f4 fzero = {0.f, 0.f, 0.f, 0.f};

  f4 acc[4][2];
#pragma unroll
  for (int tm = 0; tm < 4; ++tm)
#pragma unroll
    for (int tn = 0; tn < 2; ++tn) acc[tm][tn] = fzero;

#pragma unroll
  for (int kk = 0; kk < 256; kk += 32) {
    bf8 af[4], bfr[2];
#pragma unroll
    for (int tm = 0; tm < 4; ++tm)
      af[tm] = *(const bf8*)(ob + (size_t)(M0 + wm * 64 + tm * 16 + l15) * 256 + kk + lq * 8);
#pragma unroll
    for (int tn = 0; tn < 2; ++tn)
      bfr[tn] = *(const bf8*)(Wot + (size_t)(N0 + wn * 32 + tn * 16 + l15) * 256 + kk + lq * 8);
#pragma unroll
    for (int tm = 0; tm < 4; ++tm)
#pragma unroll
      for (int tn = 0; tn < 2; ++tn)
        acc[tm][tn] = __builtin_amdgcn_mfma_f32_16x16x32_bf16(af[tm], bfr[tn], acc[tm][tn], 0, 0, 0);
  }

#pragma unroll
  for (int tn = 0; tn < 2; ++tn) {
    const int n = N0 + wn * 32 + tn * 16 + l15;
    const float bias = bo[n];
#pragma unroll
    for (int tm = 0; tm < 4; ++tm)
#pragma unroll
      for (int r = 0; r < 4; ++r) {
        const int m = M0 + wm * 64 + tm * 16 + lq * 4 + r;
        out[(size_t)m * 256 + n] = acc[tm][tn][r] + bias;
      }
  }
}

extern "C" void kernel_launch(void* const* d_in, const int* in_sizes, int n_in,
                              void* d_out, int out_size, void* d_ws, size_t ws_size,
                              hipStream_t stream) {
  const float* h = (const float*)d_in[0];
  const float* edges = (const float*)d_in[1];
  const int* dmask = (const int*)d_in[2];
  const int* kmask = (const int*)d_in[3];
  const float* Wq = (const float*)d_in[4];
  const float* bq = (const float*)d_in[5];
  const float* Wk = (const float*)d_in[6];
  const float* bk = (const float*)d_in[7];
  const float* Wv = (const float*)d_in[8];
  const float* bv = (const float*)d_in[9];
  const float* Wo = (const float*)d_in[10];
  const float* bo = (const float*)d_in[11];
  const float* Wp = (const float*)d_in[12];
  const float* bp = (const float*)d_in[13];

  char* ws = (char*)d_ws;
  __bf16* hb = (__bf16*)(ws);                                // 4 MB (reused as ow)
  __bf16* Wt = (__bf16*)(ws + ((size_t)4 << 20));            // 384 KB
  __bf16* Wot = (__bf16*)(ws + ((size_t)4 << 20) + 768 * 256 * 2);  // 128 KB
  __bf16* qw = (__bf16*)(ws + ((size_t)5 << 20));            // 4 MB
  __bf16* kw = (__bf16*)(ws + ((size_t)9 << 20));            // 4 MB
  __bf16* vtw = (__bf16*)(ws + ((size_t)13 << 20));          // 4 MB
  unsigned int* posp = (unsigned int*)(ws + ((size_t)32 << 20));  // 64 MB pos pages
  __bf16* ow = hb;  // h cast is consumed by qkv_gemm before attn writes O

  float* out = (float*)d_out;
  float* attn = out + (size_t)kB * kN * kD;

  cast_h_kernel<<<1024, 256, 0, stream>>>(h, hb);
  prep_w_kernel<<<1024, 256, 0, stream>>>(Wq, Wk, Wv, Wo, Wt, Wot);
  qkv_gemm_kernel<<<dim3(64, 12), 256, 0, stream>>>(hb, Wt, bq, bk, bv, qw, kw, vtw);
  prep_pos_kernel<<<kB * kN, 256, 0, stream>>>(edges, dmask, kmask, Wp, bp, posp);
  attn_fused_kernel<<<512, 512, 0, stream>>>(qw, kw, vtw, posp, attn, ow);
  out_gemm_kernel<<<dim3(64, 4), 256, 0, stream>>>(ow, Wot, bo, out);
}

// Round 4
// 538.906 us; speedup vs baseline: 1.0206x; 1.0022x over previous
//
#include <hip/hip_runtime.h>
#include <hip/hip_bf16.h>

constexpr int kB = 16, kN = 512, kD = 256, kH = 8, kE = 16, kDH = 32;

typedef float f4 __attribute__((ext_vector_type(4)));
typedef __bf16 bf8 __attribute__((ext_vector_type(8)));

__device__ __forceinline__ void gload16(const void* g, const void* l) {
  __builtin_amdgcn_global_load_lds(
      (const __attribute__((address_space(1))) void*)g,
      (__attribute__((address_space(3))) void*)l, 16, 0, 0);
}

// ---------------- P1: cast h (fp32) -> bf16 ----------------
__global__ __launch_bounds__(256) void cast_h_kernel(const float* __restrict__ h,
                                                     __bf16* __restrict__ hb) {
  const int idx = (blockIdx.x * 256 + threadIdx.x) * 8;
  f4 a = *(const f4*)(h + idx);
  f4 b = *(const f4*)(h + idx + 4);
  bf8 o;
  o[0] = (__bf16)a[0]; o[1] = (__bf16)a[1]; o[2] = (__bf16)a[2]; o[3] = (__bf16)a[3];
  o[4] = (__bf16)b[0]; o[5] = (__bf16)b[1]; o[6] = (__bf16)b[2]; o[7] = (__bf16)b[3];
  *(bf8*)(hb + idx) = o;
}

// ---------------- P2: weights -> bf16, transposed [n][k] ----------------
__global__ __launch_bounds__(256) void prep_w_kernel(
    const float* __restrict__ Wq, const float* __restrict__ Wk,
    const float* __restrict__ Wv, const float* __restrict__ Wo,
    __bf16* __restrict__ Wt, __bf16* __restrict__ Wot) {
  const int r = blockIdx.x;
  const int t = threadIdx.x;
  if (r < 768) {
    const float* src = (r < 256) ? Wq : (r < 512) ? Wk : Wv;
    const int c = r & 255;
    Wt[(size_t)r * 256 + t] = (__bf16)src[(size_t)t * 256 + c];
  } else {
    const int rr = r - 768;
    Wot[(size_t)rr * 256 + t] = (__bf16)Wo[(size_t)t * 256 + rr];
  }
}

// ---------------- P3: pos = (edges@Wp + bp)*RS8, masks baked, bf16 ----------------
// R4: 4 consecutive n-rows per block (grid 2048). The attn fragment's uint4
// component index is exactly n&3, so the block accumulates all 4 components in
// registers and writes pos DIRECTLY in MFMA-fragment order with one coalesced
// 16B store per (h2, m):
//   posp4[uint4] : [b][h2(4)][ntile(32)][kt(32)][lane(64)], component r,
//   where lane = (m&15) + 16*((n&15)>>2), r = n&3, value = packed bf16 head pair.
// Edges staged transposed [e4][c] via per-lane gload_lds src (dest linear) so
// the compute-side ds_read_b128 is lane-linear = conflict-free. Ping-pong
// buffers, 1 barrier/row, vmcnt(0) covers only the current row.
__global__ __launch_bounds__(256) void prep_pos_kernel(
    const float* __restrict__ edges, const int* __restrict__ dmask,
    const int* __restrict__ kmask, const float* __restrict__ Wp,
    const float* __restrict__ bp, uint4* __restrict__ posp4) {
  const int blk = blockIdx.x;  // b * 128 + ng
  const int b = blk >> 7;
  const int ng = blk & 127;    // 4-row group
  const int nbase = ng * 4;
  const int tid = threadIdx.x;

  __shared__ __align__(16) float stg[2][8192];  // [buf][e4(4)][c(512)][4f] = 32KB each

  const float RS8 = 0.35355339059327373f;  // 1/sqrt(H)

#define ISSUE_ROW(RR, BUF)                                                        \
  {                                                                               \
    const float* rowg_ = edges + (size_t)(b * kN + nbase + (RR)) * (kN * kE);     \
    _Pragma("unroll") for (int j_ = 0; j_ < 8; ++j_) {                            \
      const int e4_ = j_ >> 1;                                                    \
      const int c_ = (j_ & 1) * 256 + tid;                                        \
      gload16(rowg_ + c_ * 16 + e4_ * 4,                                          \
              (const char*)&stg[BUF][0] + j_ * 4096 + tid * 16);                  \
    }                                                                             \
  }

  // masks first (retire before the row gloads; loop vmcnt counts stay exact)
  int km[2], dm[4][2];
#pragma unroll
  for (int half = 0; half < 2; ++half) km[half] = kmask[b * kN + half * 256 + tid];
#pragma unroll
  for (int rr = 0; rr < 4; ++rr)
#pragma unroll
    for (int half = 0; half < 2; ++half)
      dm[rr][half] = dmask[(size_t)(b * kN + nbase + rr) * kN + half * 256 + tid];

  float bph[8];
#pragma unroll
  for (int hh = 0; hh < 8; ++hh) bph[hh] = bp[hh] * RS8;

  ISSUE_ROW(0, 0);

  uint4 w4[2][4];  // [half][h2], component rr filled per row

#pragma unroll
  for (int rr = 0; rr < 4; ++rr) {
    const int buf = rr & 1;
    __asm__ __volatile__("s_waitcnt vmcnt(0)" ::: "memory");
    __builtin_amdgcn_s_barrier();
    __builtin_amdgcn_sched_barrier(0);
    if (rr < 3) ISSUE_ROW(rr + 1, buf ^ 1);

#pragma unroll
    for (int half = 0; half < 2; ++half) {
      const int c = half * 256 + tid;
      const bool valid = (dm[rr][half] != 0) && (km[half] != 0);
      float acc[8];
#pragma unroll
      for (int hh = 0; hh < 8; ++hh) acc[hh] = 0.f;
#pragma unroll
      for (int e4 = 0; e4 < 4; ++e4) {
        f4 ev = *(const f4*)(&stg[buf][e4 * 2048 + c * 4]);
#pragma unroll
        for (int i = 0; i < 4; ++i) {
          const float e_ = ev[i];
#pragma unroll
          for (int hh = 0; hh < 8; ++hh)
            acc[hh] = fmaf(e_, Wp[(e4 * 4 + i) * kH + hh], acc[hh]);
        }
      }
#pragma unroll
      for (int pp = 0; pp < 4; ++pp) {
        const float lo = valid ? fmaf(acc[2 * pp], RS8, bph[2 * pp]) : -1e9f;
        const float hi = valid ? fmaf(acc[2 * pp + 1], RS8, bph[2 * pp + 1]) : -1e9f;
        union { __bf16 h2[2]; unsigned int u; } pk;
        pk.h2[0] = (__bf16)lo;
        pk.h2[1] = (__bf16)hi;
        ((unsigned int*)&w4[half][pp])[rr] = pk.u;
      }
    }
  }
#undef ISSUE_ROW

  // coalesced fragment-order stores: one uint4 per (half, h2)
  const int nt = ng >> 2;
  const int qq2 = ng & 3;
#pragma unroll
  for (int half = 0; half < 2; ++half) {
    const int c = half * 256 + tid;
    const size_t base =
        ((((size_t)(b * 4) * 32 + nt) * 32 + (c >> 4)) * 64) + (c & 15) + 16 * qq2;
#pragma unroll
    for (int pp = 0; pp < 4; ++pp)
      posp4[base + (size_t)pp * (32 * 32 * 64)] = w4[half][pp];
  }
}

// ---------------- K1: QKV projection GEMM (M=8192, N=768, K=256) ----------------
__global__ __launch_bounds__(256, 4) void qkv_gemm_kernel(
    const __bf16* __restrict__ hb, const __bf16* __restrict__ Wt,
    const float* __restrict__ bq, const float* __restrict__ bk,
    const float* __restrict__ bv,
    __bf16* __restrict__ qw, __bf16* __restrict__ kw, __bf16* __restrict__ vtw) {
  const int M0 = blockIdx.x * 128;
  const int N0 = blockIdx.y * 64;
  const int tid = threadIdx.x;
  const int wave = tid >> 6, lane = tid & 63;
  const int l15 = lane & 15, lq = lane >> 4;
  const int wm = wave & 1, wn = wave >> 1;
  const f4 fzero = {0.f, 0.f, 0.f, 0.f};

  f4 acc[4][2];
#pragma unroll
  for (int tm = 0; tm < 4; ++tm)
#pragma unroll
    for (int tn = 0; tn < 2; ++tn) acc[tm][tn] = fzero;

#pragma unroll
  for (int kk = 0; kk < 256; kk += 32) {
    bf8 af[4], bfr[2];
#pragma unroll
    for (int tm = 0; tm < 4; ++tm)
      af[tm] = *(const bf8*)(hb + (size_t)(M0 + wm * 64 + tm * 16 + l15) * 256 + kk + lq * 8);
#pragma unroll
    for (int tn = 0; tn < 2; ++tn)
      bfr[tn] = *(const bf8*)(Wt + (size_t)(N0 + wn * 32 + tn * 16 + l15) * 256 + kk + lq * 8);
#pragma unroll
    for (int tm = 0; tm < 4; ++tm)
#pragma unroll
      for (int tn = 0; tn < 2; ++tn)
        acc[tm][tn] = __builtin_amdgcn_mfma_f32_16x16x32_bf16(af[tm], bfr[tn], acc[tm][tn], 0, 0, 0);
  }

  const float QS = 0.17677669529663687f;  // 1/sqrt(DH)
  const int wsel = N0 >> 8;               // 0:q 1:k 2:v
#pragma unroll
  for (int tn = 0; tn < 2; ++tn) {
    const int n = N0 + wn * 32 + tn * 16 + l15;
    const int c = n & 255;
    const float bias = (wsel == 0) ? bq[c] : (wsel == 1) ? bk[c] : bv[c];
#pragma unroll
    for (int tm = 0; tm < 4; ++tm) {
#pragma unroll
      for (int r = 0; r < 4; ++r) {
        const int m = M0 + wm * 64 + tm * 16 + lq * 4 + r;
        const float v = acc[tm][tn][r] + bias;
        if (wsel == 0) {
          qw[(size_t)m * 256 + c] = (__bf16)(v * QS);
        } else if (wsel == 1) {
          kw[(size_t)m * 256 + c] = (__bf16)v;
        } else {
          const int b_ = m >> 9, nn_ = m & 511, hh = c >> 5, dd = c & 31;
          vtw[(((size_t)b_ * kH + hh) * kDH + dd) * kN + nn_] = (__bf16)v;
        }
      }
    }
  }
}

// ---------------- K2: fused QK^T + pos-init + softmax + attn-write + P@V ----------------
// Grid: 512 blocks (b, 16-query tile). 8 waves = 8 heads. Scores in 128 AGPR/lane.
// R4: sc init = 32 fully-coalesced uint4 loads (fragment-order posp4, 1KB/instr).
__global__ __launch_bounds__(512, 2) void attn_fused_kernel(
    const __bf16* __restrict__ qw, const __bf16* __restrict__ kw,
    const __bf16* __restrict__ vtw, const uint4* __restrict__ posp4,
    float* __restrict__ attn_out, __bf16* __restrict__ ow) {
  const int blk = blockIdx.x;
  const int b = blk >> 5;
  const int n0 = (blk & 31) * 16;
  const int tid = threadIdx.x;
  const int wave = tid >> 6, lane = tid & 63;
  const int l15 = lane & 15, lq = lane >> 4;

  __shared__ __align__(16) __bf16 p[8][16][136];  // phase-4 P tiles (wave-private rows)

  f4 sc[32];  // scores: sc[kt][r] = S[q = lq*4+r][key = kt*16+l15]

  // ---- phase 1: sc init from fragment-order pos (bf16 head pairs) ----
  const uint4* pw =
      posp4 + (((size_t)(b * 4 + (wave >> 1)) * 32 + (n0 >> 4)) * 32) * 64 + lane;
  const int hlo = wave & 1;
#pragma unroll
  for (int c8 = 0; c8 < 4; ++c8) {
    uint4 u[8];
#pragma unroll
    for (int j = 0; j < 8; ++j) u[j] = pw[(size_t)(c8 * 8 + j) * 64];
#pragma unroll
    for (int j = 0; j < 8; ++j) {
#pragma unroll
      for (int r = 0; r < 4; ++r) {
        const unsigned int uu = ((const unsigned int*)&u[j])[r];
        sc[c8 * 8 + j][r] = __uint_as_float(hlo ? (uu & 0xffff0000u) : (uu << 16));
      }
    }
  }

  // ---- phase 2: scores += q . k^T (MFMA accumulates onto pos init) ----
  bf8 qa = *(const bf8*)(qw + ((size_t)(b * kN + n0 + l15) * kH + wave) * kDH + lq * 8);
#pragma unroll
  for (int kt = 0; kt < 32; ++kt) {
    bf8 kb = *(const bf8*)(kw + ((size_t)(b * kN + kt * 16 + l15) * kH + wave) * kDH + lq * 8);
    sc[kt] = __builtin_amdgcn_mfma_f32_16x16x32_bf16(qa, kb, sc[kt], 0, 0, 0);
  }

  // ---- phase 3: row softmax (cross-lane over 16 lanes sharing a row) ----
  float inv[4];
#pragma unroll
  for (int r = 0; r < 4; ++r) {
    float m_ = sc[0][r];
#pragma unroll
    for (int kt = 1; kt < 32; ++kt) m_ = fmaxf(m_, sc[kt][r]);
#pragma unroll
    for (int s = 1; s < 16; s <<= 1) m_ = fmaxf(m_, __shfl_xor(m_, s, 16));
    float s_ = 0.f;
#pragma unroll
    for (int kt = 0; kt < 32; ++kt) {
      const float e_ = __expf(sc[kt][r] - m_);
      sc[kt][r] = e_;
      s_ += e_;
    }
#pragma unroll
    for (int s = 1; s < 16; s <<= 1) s_ += __shfl_xor(s_, s, 16);
    inv[r] = 1.0f / s_;
  }

  // ---- phase 4: write attn (fp32), P->LDS (bf16, wave-private), P@V MFMA ----
  const f4 fzero = {0.f, 0.f, 0.f, 0.f};
  f4 oacc[2];
  oacc[0] = fzero; oacc[1] = fzero;
  float* attn_base = attn_out + ((size_t)(b * kH + wave) * kN + n0) * kN;
#pragma unroll
  for (int cc = 0; cc < 4; ++cc) {
#pragma unroll
    for (int kl = 0; kl < 8; ++kl) {
      const int kt = cc * 8 + kl;
#pragma unroll
      for (int r = 0; r < 4; ++r) {
        const float pv = sc[kt][r] * inv[r];
        attn_base[(size_t)(lq * 4 + r) * kN + kt * 16 + l15] = pv;
        p[wave][lq * 4 + r][kl * 16 + l15] = (__bf16)pv;
      }
    }
    // Same-wave cross-lane LDS RAW: force write completion, forbid hoisting.
    __asm__ __volatile__("s_waitcnt lgkmcnt(0)" ::: "memory");
#pragma unroll
    for (int mc = 0; mc < 4; ++mc) {
      bf8 pa = *(const bf8*)(&p[wave][l15][mc * 32 + lq * 8]);
#pragma unroll
      for (int dd = 0; dd < 2; ++dd) {
        bf8 vb = *(const bf8*)(vtw + (((size_t)(b * kH + wave) * kDH) + dd * 16 + l15) * kN +
                               cc * 128 + mc * 32 + lq * 8);
        oacc[dd] = __builtin_amdgcn_mfma_f32_16x16x32_bf16(pa, vb, oacc[dd], 0, 0, 0);
      }
    }
  }

  // ---- phase 5: store O (bf16) for the output projection ----
#pragma unroll
  for (int dd = 0; dd < 2; ++dd)
#pragma unroll
    for (int r = 0; r < 4; ++r)
      ow[(size_t)(b * kN + n0 + lq * 4 + r) * kD + wave * kDH + dd * 16 + l15] = (__bf16)oacc[dd][r];
}

// ---------------- K3: out = O @ Wo + bo (M=8192, N=256, K=256) ----------------
__global__ __launch_bounds__(256, 4) void out_gemm_kernel(
    const __bf16* __restrict__ ob, const __bf16* __restrict__ Wot,
    const float* __restrict__ bo, float* __restrict__ out) {
  const int M0 = blockIdx.x * 128;
  const int N0 = blockIdx.y * 64;
  const int tid = threadIdx.x;
  const int wave = tid >> 6, lane = tid & 63;
  const int l15 = lane & 15, lq = lane >> 4;
  const int wm = wave & 1, wn = wave >> 1;
  const f4 fzero = {0.f, 0.f, 0.f, 0.f};

  f4 acc[4][2];
#pragma unroll
  for (int tm = 0; tm < 4; ++tm)
#pragma unroll
    for (int tn = 0; tn < 2; ++tn) acc[tm][tn] = fzero;

#pragma unroll
  for (int kk = 0; kk < 256; kk += 32) {
    bf8 af[4], bfr[2];
#pragma unroll
    for (int tm = 0; tm < 4; ++tm)
      af[tm] = *(const bf8*)(ob + (size_t)(M0 + wm * 64 + tm * 16 + l15) * 256 + kk + lq * 8);
#pragma unroll
    for (int tn = 0; tn < 2; ++tn)
      bfr[tn] = *(const bf8*)(Wot + (size_t)(N0 + wn * 32 + tn * 16 + l15) * 256 + kk + lq * 8);
#pragma unroll
    for (int tm = 0; tm < 4; ++tm)
#pragma unroll
      for (int tn = 0; tn < 2; ++tn)
        acc[tm][tn] = __builtin_amdgcn_mfma_f32_16x16x32_bf16(af[tm], bfr[tn], acc[tm][tn], 0, 0, 0);
  }

#pragma unroll
  for (int tn = 0; tn < 2; ++tn) {
    const int n = N0 + wn * 32 + tn * 16 + l15;
    const float bias = bo[n];
#pragma unroll
    for (int tm = 0; tm < 4; ++tm)
#pragma unroll
      for (int r = 0; r < 4; ++r) {
        const int m = M0 + wm * 64 + tm * 16 + lq * 4 + r;
        out[(size_t)m * 256 + n] = acc[tm][tn][r] + bias;
      }
  }
}

extern "C" void kernel_launch(void* const* d_in, const int* in_sizes, int n_in,
                              void* d_out, int out_size, void* d_ws, size_t ws_size,
                              hipStream_t stream) {
  const float* h = (const float*)d_in[0];
  const float* edges = (const float*)d_in[1];
  const int* dmask = (const int*)d_in[2];
  const int* kmask = (const int*)d_in[3];
  const float* Wq = (const float*)d_in[4];
  const float* bq = (const float*)d_in[5];
  const float* Wk = (const float*)d_in[6];
  const float* bk = (const float*)d_in[7];
  const float* Wv = (const float*)d_in[8];
  const float* bv = (const float*)d_in[9];
  const float* Wo = (const float*)d_in[10];
  const float* bo = (const float*)d_in[11];
  const float* Wp = (const float*)d_in[12];
  const float* bp = (const float*)d_in[13];

  char* ws = (char*)d_ws;
  __bf16* hb = (__bf16*)(ws);                                // 4 MB (reused as ow)
  __bf16* Wt = (__bf16*)(ws + ((size_t)4 << 20));            // 384 KB
  __bf16* Wot = (__bf16*)(ws + ((size_t)4 << 20) + 768 * 256 * 2);  // 128 KB
  __bf16* qw = (__bf16*)(ws + ((size_t)5 << 20));            // 4 MB
  __bf16* kw = (__bf16*)(ws + ((size_t)9 << 20));            // 4 MB
  __bf16* vtw = (__bf16*)(ws + ((size_t)13 << 20));          // 4 MB
  uint4* posp4 = (uint4*)(ws + ((size_t)32 << 20));          // 64 MB pos fragments
  __bf16* ow = hb;  // h cast is consumed by qkv_gemm before attn writes O

  float* out = (float*)d_out;
  float* attn = out + (size_t)kB * kN * kD;

  cast_h_kernel<<<1024, 256, 0, stream>>>(h, hb);
  prep_w_kernel<<<1024, 256, 0, stream>>>(Wq, Wk, Wv, Wo, Wt, Wot);
  qkv_gemm_kernel<<<dim3(64, 12), 256, 0, stream>>>(hb, Wt, bq, bk, bv, qw, kw, vtw);
  prep_pos_kernel<<<kB * kN / 4, 256, 0, stream>>>(edges, dmask, kmask, Wp, bp, posp4);
  attn_fused_kernel<<<512, 512, 0, stream>>>(qw, kw, vtw, posp4, attn, ow);
  out_gemm_kernel<<<dim3(64, 4), 256, 0, stream>>>(ow, Wot, bo, out);
}